// Round 4
// baseline (208.012 us; speedup 1.0000x reference)
//
#include <hip/hip_runtime.h>
#include <hip/hip_bf16.h>
#include <math.h>

#define NB 2
#define NC 256
#define HWIN 4096
#define NN 4096
#define ND 32
#define NHH 4
#define EPSV 1e-5f

typedef short short8 __attribute__((ext_vector_type(8)));
typedef float f32x4 __attribute__((ext_vector_type(4)));
typedef unsigned short u16;
typedef unsigned int u32;

// workspace offsets (float32 units)
#define OFF_T1   0          // 131072
#define OFF_T2   262144     // 524288
#define OFF_Q    1310720    // 524288 (bf16 x 1048576)
#define OFF_KT1  1835008    // 65536
#define OFF_VT1  1900544    // 65536
#define OFF_KT2  1966080    // 262144
#define OFF_VT2  2228224    // 262144
#define OFF_RCT1 2490368    // 40960
#define OFF_RCT2 2531328    // 163840
#define OFF_PO   2826240    // 2097152 u32: po[chunk][32768 rows][16]
#define OFF_PS   4923392    // 131072: ps[chunk][32768 rows]
// end ~20.2 MB

#define QSCALE 0.2550437314857726f   // 1/sqrt(32) * log2(e)
#define LOG2E  1.4426950408889634f

__device__ __forceinline__ u16 f2bf(float x) {   // f32 -> bf16 RNE
  unsigned u = __float_as_uint(x);
  u += 0x7fffu + ((u >> 16) & 1u);
  return (u16)(u >> 16);
}

__device__ __forceinline__ u32 pk_bf16(float a, float b) {  // packed RNE cvt
  __hip_bfloat162 h = __float22bfloat162_rn(make_float2(a, b));
  u32 r; __builtin_memcpy(&r, &h, 4);
  return r;
}

__device__ __forceinline__ float keysw(float t) {  // Keys cubic, a=-0.5
  t = fabsf(t);
  float w;
  if (t < 1.f)       w = ((1.5f*t - 2.5f)*t)*t + 1.f;
  else if (t < 2.f)  w = ((-0.5f*t + 2.5f)*t - 4.f)*t + 2.f;
  else               w = 0.f;
  return w;
}

// ---------- device bodies ----------
template<int KS, int STR, int PAD, int OH>
__device__ __forceinline__ void dwconv_body(int idx, const float* __restrict__ x,
    const float* __restrict__ dww, const float* __restrict__ bn1,
    const float* __restrict__ pww, const float* __restrict__ bn2,
    float* __restrict__ tout) {
  const int hw = OH*OH;
  int s = idx % hw; int c = (idx/hw) % NC; int b = idx/(hw*NC);
  int oy = s / OH, ox = s % OH;
  const float* xp = x + (b*NC + c)*HWIN;
  const float* wp = dww + c*KS*KS;
  float acc = 0.f;
  #pragma unroll
  for (int ky = 0; ky < KS; ++ky) {
    int iy = oy*STR - PAD + ky;
    if (iy < 0 || iy >= 64) continue;
    #pragma unroll
    for (int kx = 0; kx < KS; ++kx) {
      int ix = ox*STR - PAD + kx;
      if (ix < 0 || ix >= 64) continue;
      acc += xp[iy*64 + ix] * wp[ky*KS + kx];
    }
  }
  float s1 = bn1[c] * rsqrtf(bn1[3*NC + c] + EPSV);
  float z = (acc - bn1[2*NC + c])*s1 + bn1[NC + c];
  z = fmaxf(z, 0.f);
  float s2 = bn2[c] * rsqrtf(bn2[3*NC + c] + EPSV);
  z = z * (pww[c]*s2) + (bn2[NC + c] - bn2[2*NC + c]*s2);
  tout[idx] = z;
}

__device__ __forceinline__ void rpe_body(int idx, const float* __restrict__ rpe,
                                         u16* __restrict__ rcT, int L, int ch) {
  int r = idx & 63; int l = (idx >> 6) % L; int b = idx / (64*L);
  float f = ((float)l + 0.5f)*(64.f/(float)L) - 0.5f;
  int i0 = (int)floorf(f) - 1;
  const float* rp = rpe + ((b*2 + ch)*64 + r)*64;
  float v = 0.f, wsum = 0.f;
  #pragma unroll
  for (int j = 0; j < 4; ++j) {
    int i = i0 + j;
    if (i >= 0 && i < 64) {
      float w = keysw(f - (float)i);
      v += w * rp[i]; wsum += w;
    }
  }
  rcT[((size_t)(b*L + l))*80 + 4 + r] = f2bf(v / wsum);
}

// ---------- stage 1: dwconv1 + dwconv2 + rpe1 + rpe2 ----------
// (kvw/qw transposes removed: localkv now reads the original [o][c] layouts
// directly with float4 loads.)
__global__ void __launch_bounds__(256) prep_kernel(
    const float* __restrict__ x,
    const float* __restrict__ dw1, const float* __restrict__ bn11,
    const float* __restrict__ pw1, const float* __restrict__ bn12, float* __restrict__ t1,
    const float* __restrict__ dw2, const float* __restrict__ bn21,
    const float* __restrict__ pw2, const float* __restrict__ bn22, float* __restrict__ t2,
    const float* __restrict__ rpe, u16* __restrict__ rct1, u16* __restrict__ rct2) {
  int blk = blockIdx.x;
  int t = threadIdx.x;
  if (blk < 512) {
    dwconv_body<7,4,3,16>(blk*256 + t, x, dw1, bn11, pw1, bn12, t1);
  } else if (blk < 2560) {
    dwconv_body<5,2,2,32>((blk-512)*256 + t, x, dw2, bn21, pw2, bn22, t2);
  } else if (blk < 2816) {
    rpe_body((blk-2560)*256 + t, rpe, rct1, 512, 0);
  } else {
    rpe_body((blk-2816)*256 + t, rpe, rct2, 2048, 1);
  }
}

// ---------- stage 2: fused local 3x3 + kv 1x1 (both branches) + q 1x1 ----------
// blocks [0,640): strip blocks, PAIRED: even=K half, odd=V half (stage A local
//   conv recomputed by both). blocks [640,1664): q conv, 8 spatial/block.
// Stage B reads weights DIRECTLY from kvw/qw ([o][c], c-contiguous) as float4:
// 64 loads/thread instead of 256 scalar column loads (the round-3 latency
// chain: 1 load + 16cy VALU per link -> 1 load + 128cy per link, L1-resident).
__global__ void __launch_bounds__(256) localkv_kernel(
    const float* __restrict__ t1in, const float* __restrict__ t2in,
    const float* __restrict__ lw, const float* __restrict__ lb,
    const float* __restrict__ kvw, const float* __restrict__ kvb,
    u16* __restrict__ kt1, u16* __restrict__ vt1,
    u16* __restrict__ kt2, u16* __restrict__ vt2,
    const float* __restrict__ x, const float* __restrict__ qw,
    const float* __restrict__ qb, u16* __restrict__ q) {
  __shared__ float sbuf[NC*8];   // 8KB
  int blk = blockIdx.x, tid = threadIdx.x;
  if (blk < 640) {
    // ---- fused local+kv over an 8-spatial strip; this block does K or V ----
    int si = blk >> 1, kv = blk & 1;
    const float* tin; u16 *kT, *vT; int OH, hw, b, s0;
    if (si < 64) { tin = t1in; kT = kt1; vT = vt1; OH = 16; hw = 256;  b = si >> 5;  s0 = (si & 31)*8; }
    else { int v = si-64; tin = t2in; kT = kt2; vT = vt2; OH = 32; hw = 1024; b = v >> 7; s0 = (v & 127)*8; }
    int oy = s0 / OH, ox0 = s0 % OH;
    // stage A: y(strip) -> LDS, stride 8 (2-way LDS aliasing = free)
    int ci = tid >> 3, i = tid & 7;
    int ox = ox0 + i;
    #pragma unroll
    for (int p = 0; p < 8; ++p) {
      int c = p*32 + ci;
      const float* tp = tin + (b*NC + c)*hw;
      const float* wp = lw + c*9;
      float acc = lb[c];
      #pragma unroll
      for (int dy = 0; dy < 3; ++dy) {
        int iy = oy + dy - 1;
        if (iy < 0 || iy >= OH) continue;
        #pragma unroll
        for (int dx = 0; dx < 3; ++dx) {
          int ix = ox + dx - 1;
          if (ix < 0 || ix >= OH) continue;
          acc += tp[iy*OH + ix]*wp[dy*3 + dx];
        }
      }
      acc += tp[oy*OH + ox];
      sbuf[c*8 + i] = acc;
    }
    __syncthreads();
    // stage B: this thread computes output row o = tid + kv*256, 8 spatial.
    float acc[8];
    float bias = kvb[tid + kv*256];
    #pragma unroll
    for (int j = 0; j < 8; ++j) acc[j] = bias;
    const float* wrow = kvw + (size_t)(tid + kv*256)*256;   // c-contiguous
    #pragma unroll 4
    for (int c4 = 0; c4 < 64; ++c4) {
      float4 w4 = *(const float4*)(wrow + c4*4);
      #pragma unroll
      for (int j = 0; j < 4; ++j) {
        int c = c4*4 + j;
        f32x4 ya = *(const f32x4*)(sbuf + c*8);
        f32x4 yb = *(const f32x4*)(sbuf + c*8 + 4);
        float wv = (j == 0) ? w4.x : (j == 1) ? w4.y : (j == 2) ? w4.z : w4.w;
        #pragma unroll
        for (int jj = 0; jj < 4; ++jj) { acc[jj] += wv*ya[jj]; acc[4+jj] += wv*yb[jj]; }
      }
    }
    int hh2 = tid >> 6, r = tid & 63, d = r >> 1, e = r & 1;
    int L = 2*hw;
    if (kv == 0) {
      u16* kp = kT + ((size_t)((b*NHH + hh2)*L + e*hw + s0))*ND + d;
      #pragma unroll
      for (int j = 0; j < 8; ++j) kp[j*ND] = f2bf(acc[j]);
    } else {
      // V tiled write: l = e*hw + s0 + j, tile = l>>6 (const per thread)
      int l0v = e*hw + s0;
      u16* vp = vT + ((size_t)((b*NHH + hh2)*(L/64) + (l0v >> 6))*ND + d)*64 + (l0v & 63);
      #pragma unroll
      for (int j = 0; j < 8; ++j) vp[j] = f2bf(acc[j]);
    }
  } else {
    // ---- q conv: 8 spatial/block, float4 weight loads from qw [oc][c] ----
    int blk2 = blk - 640;           // 0..1023
    int b = blk2 >> 9;
    int n0 = (blk2 & 511) * 8;
    #pragma unroll
    for (int j = 0; j < 8; ++j) {
      int idx = tid + 256*j;
      int c = idx >> 3, i = idx & 7;
      sbuf[idx] = x[(b*NC + c)*HWIN + n0 + i];
    }
    __syncthreads();
    int sph = tid >> 7, oc = tid & 127;    // sph: spatial half (4 each)
    float bias = qb[oc];
    float acc[4];
    #pragma unroll
    for (int i = 0; i < 4; ++i) acc[i] = bias;
    const float* wrow = qw + (size_t)oc*256;       // c-contiguous
    #pragma unroll 4
    for (int c4 = 0; c4 < 64; ++c4) {
      float4 w4 = *(const float4*)(wrow + c4*4);
      #pragma unroll
      for (int j = 0; j < 4; ++j) {
        int c = c4*4 + j;
        f32x4 yv = *(const f32x4*)(sbuf + c*8 + sph*4);
        float wv = (j == 0) ? w4.x : (j == 1) ? w4.y : (j == 2) ? w4.z : w4.w;
        #pragma unroll
        for (int i = 0; i < 4; ++i) acc[i] += wv * yv[i];
      }
    }
    int h = oc >> 5, d = oc & 31;
    u16* qp = q + (((size_t)(b*NHH + h))*NN + n0 + sph*4)*ND + d;
    #pragma unroll
    for (int i = 0; i < 4; ++i) qp[i*ND] = f2bf(acc[i]*QSCALE);
  }
}

// ---------- stage 3: MFMA flash attention ----------
// Single-buffered LDS K/V, reg prefetch, 2 barriers/iter; raw v_exp_f32;
// XOR-swizzled LDS (conflict-free); V staged from tiled global layout.
// K tile 64 rows x 64B:  byte = row*64  + (cb ^ (((row>>1)&3)<<4))
// V tile 32 rows x 128B: byte = row*128 + (cb ^ ((row&7)<<4))
// P tile 16 rows x 128B: byte = row*128 + (cb ^ ((row&7)<<4))
__global__ void __launch_bounds__(256) attn_kernel(
    const u16* __restrict__ qbf,
    const u16* __restrict__ kt1, const u16* __restrict__ vt1, const u16* __restrict__ rct1,
    const u16* __restrict__ kt2, const u16* __restrict__ vt2, const u16* __restrict__ rct2,
    u32* __restrict__ po32, float* __restrict__ ps,
    float* __restrict__ out) {
  __shared__ u16 kbuf[64*32];          // K tile, swizzled, 4KB
  __shared__ u16 vbuf[32*64];          // V tile, swizzled, 4KB
  __shared__ u32 pbuf_all[4][16*32];   // per-wave P^T tile, swizzled, 2KB/wave
  int u = blockIdx.x;
  int br, b, hh, rb, chunk;
  if (u < 512) { br = 0; b = u >> 8; hh = (u >> 6) & 3; rb = u & 63; chunk = 0; }
  else { int v = u - 512; br = 1; chunk = v & 3; rb = (v >> 2) & 63; hh = (v >> 8) & 3; b = v >> 10; }
  int L = br ? 2048 : 512;
  const u16* kT  = br ? kt2 : kt1;
  const u16* vT  = br ? vt2 : vt1;
  const u16* rcT = br ? rct2 : rct1;
  int l0base = chunk * 512;
  int tid = threadIdx.x;
  int w = tid >> 6, lane = tid & 63;
  int g = lane >> 4, lo = lane & 15;
  u32* pbuf = pbuf_all[w];
  u16* pbuf16 = (u16*)pbuf;
  int n = rb*64 + w*16 + lo;

  const u16* kbase = kT + (size_t)(b*NHH + hh)*L*ND;
  const u16* vbase = vT + (size_t)(b*NHH + hh)*ND*L;   // tiled: [L/64][32][64]
  const u16* rcTb  = rcT + (size_t)b*L*80;

  // Q B-frag (pre-scaled by 1/sqrt(32)*log2e)
  short8 qf = *(const short8*)(qbf + (((size_t)(b*NHH + hh))*NN + n)*ND + 8*g);

  // tap-weight B-frag for RPE ext-MFMA
  float fr = ((float)n + 0.5f)*(1.f/64.f) - 0.5f;
  int ri0 = (int)floorf(fr) - 1;
  int a = (w < 2) ? rb - 2 : rb - 1;     // wave-uniform floor(fr(q0)) - 1
  int rmin = a & ~3;
  float wr4[4]; float wsum = 0.f;
  #pragma unroll
  for (int j = 0; j < 4; ++j) {
    int i = ri0 + j;
    float wv = (i >= 0 && i < 64) ? keysw(fr - (float)i) : 0.f;
    wr4[j] = wv; wsum += wv;
  }
  float invw = LOG2E / wsum;
  float wt8[8];
  #pragma unroll
  for (int s = 0; s < 8; ++s) {
    float acc = 0.f;
    #pragma unroll
    for (int j = 0; j < 4; ++j)
      acc += (ri0 + j - rmin == s) ? wr4[j]*invw : 0.f;
    wt8[s] = acc;
  }
  short8 wtf;
  {
    u32 p0 = pk_bf16(wt8[0], wt8[1]), p1 = pk_bf16(wt8[2], wt8[3]);
    u32 p2 = pk_bf16(wt8[4], wt8[5]), p3 = pk_bf16(wt8[6], wt8[7]);
    uint4 uu = make_uint4(p0, p1, p2, p3);
    wtf = __builtin_bit_cast(short8, uu);
    if (g != 0) wtf = (short8)0;
  }
  const u16* rcrow0 = rcTb + (rmin + 4);

  const f32x4 zero = {0.f, 0.f, 0.f, 0.f};
  float ssum = 0.f;
  f32x4 o0 = zero, o1 = zero;

  // staging lane roles + swizzle constants
  int kr_row = tid >> 2, kr_col = (tid & 3)*8;   // K: 64 rows x 32 u16
  int kr_sw  = ((kr_row >> 1) & 3)*8;
  int vr_row = tid >> 3, vr_col = (tid & 7)*8;   // V: 32 rows x 64 u16
  int vr_sw  = (vr_row & 7)*8;
  // compute-side swizzles (row-dependent parts only)
  int ksw = ((lo >> 1) & 3)*8;                   // K row 16c+lo -> same as lo
  int vsw = (lo & 7)*8;                          // V rows lo, 16+lo share
  int psw4 = (lo & 7)*4;                         // pbuf u32 swizzle
  int psw8 = (lo & 7)*8;                         // pbuf u16 swizzle

  auto stageLoad = [&](short8& kr, short8& vr, int l0) {
    kr = *(const short8*)(kbase + (size_t)(l0 + kr_row)*ND + kr_col);
    vr = *(const short8*)(vbase + (size_t)(l0 >> 6)*(ND*64) + vr_row*64 + vr_col);
  };
  auto stageStore = [&](short8 kr, short8 vr) {
    *(short8*)(kbuf + kr_row*32 + (kr_col ^ kr_sw)) = kr;
    *(short8*)(vbuf + vr_row*64 + (vr_col ^ vr_sw)) = vr;
  };
  auto loadRC = [&](uint4 (&rc)[4], int l0) {
    #pragma unroll
    for (int c = 0; c < 4; ++c) {
      const u16* arow = rcrow0 + (size_t)(l0 + 16*c + lo)*80;
      uint2 ra = *(const uint2*)arow;
      uint2 rb2 = *(const uint2*)(arow + 4);
      rc[c] = make_uint4(ra.x, ra.y, rb2.x, rb2.y);
    }
  };

  short8 kr, vr;
  uint4 rcA[4], rcB[4];
  stageLoad(kr, vr, l0base);
  loadRC(rcA, l0base);

  for (int t = 0; t < 8; ++t) {
    stageStore(kr, vr);
    __syncthreads();
    if (t < 7) { stageLoad(kr, vr, l0base + (t+1)*64); loadRC(rcB, l0base + (t+1)*64); }
    // S tiles: rc ext-MFMA chained into K.Q MFMA
    f32x4 s4[4];
    #pragma unroll
    for (int c = 0; c < 4; ++c) {
      short8 rcf = __builtin_bit_cast(short8, rcA[c]);
      f32x4 accr = __builtin_amdgcn_mfma_f32_16x16x32_bf16(rcf, wtf, zero, 0, 0, 0);
      short8 kf = *(const short8*)(kbuf + (16*c + lo)*32 + ((8*g) ^ ksw));
      s4[c] = __builtin_amdgcn_mfma_f32_16x16x32_bf16(kf, qf, accr, 0, 0, 0);
    }
    // max-free softmax: p = exp2(s), raw v_exp_f32 (inputs bounded, P->bf16)
    float psum = 0.f;
    u32 pk[8];
    #pragma unroll
    for (int c = 0; c < 4; ++c) {
      float p0 = __builtin_amdgcn_exp2f(s4[c][0]);
      float p1 = __builtin_amdgcn_exp2f(s4[c][1]);
      float p2 = __builtin_amdgcn_exp2f(s4[c][2]);
      float p3 = __builtin_amdgcn_exp2f(s4[c][3]);
      psum += (p0 + p1) + (p2 + p3);
      pk[2*c]   = pk_bf16(p0, p1);
      pk[2*c+1] = pk_bf16(p2, p3);
    }
    ssum += psum;
    #pragma unroll
    for (int c = 0; c < 4; ++c)
      *(uint2*)(pbuf + lo*32 + ((8*c + 2*g) ^ psw4)) = make_uint2(pk[2*c], pk[2*c+1]);
    short8 pf0 = *(const short8*)(pbuf16 + lo*64 + ((8*g) ^ psw8));
    short8 pf1 = *(const short8*)(pbuf16 + lo*64 + ((32 + 8*g) ^ psw8));
    short8 v00 = *(const short8*)(vbuf + lo*64 + ((8*g) ^ vsw));
    short8 v01 = *(const short8*)(vbuf + lo*64 + ((32 + 8*g) ^ vsw));
    short8 v10 = *(const short8*)(vbuf + (16 + lo)*64 + ((8*g) ^ vsw));
    short8 v11 = *(const short8*)(vbuf + (16 + lo)*64 + ((32 + 8*g) ^ vsw));
    o0 = __builtin_amdgcn_mfma_f32_16x16x32_bf16(v00, pf0, o0, 0, 0, 0);
    o1 = __builtin_amdgcn_mfma_f32_16x16x32_bf16(v10, pf0, o1, 0, 0, 0);
    o0 = __builtin_amdgcn_mfma_f32_16x16x32_bf16(v01, pf1, o0, 0, 0, 0);
    o1 = __builtin_amdgcn_mfma_f32_16x16x32_bf16(v11, pf1, o1, 0, 0, 0);
    if (t < 7) {
      #pragma unroll
      for (int j = 0; j < 4; ++j) rcA[j] = rcB[j];
    }
    __syncthreads();   // all reads done before next tile's store
  }

  ssum += __shfl_xor(ssum, 16, 64);
  ssum += __shfl_xor(ssum, 32, 64);
  if (br == 0) {
    float inv = 1.f/ssum;
    f32x4 w0 = o0*inv, w1 = o1*inv;
    float* op = out + ((size_t)((b*NC + hh*64 + rb)*64 + (w*16 + lo)))*64;
    *(f32x4*)(op + 4*g)      = w0;
    *(f32x4*)(op + 16 + 4*g) = w1;
  } else {
    int bh = b*NHH + hh;
    int row = bh*NN + n;
    u32* pop = po32 + ((size_t)chunk*32768 + row)*16;    // chunk-major
    pop[2*g]     = pk_bf16(o0[0], o0[1]);
    pop[2*g + 1] = pk_bf16(o0[2], o0[3]);
    pop[8 + 2*g]     = pk_bf16(o1[0], o1[1]);
    pop[8 + 2*g + 1] = pk_bf16(o1[2], o1[3]);
    if (g == 0) ps[(size_t)chunk*32768 + row] = ssum;
  }
}

// ---------- stage 4: combine branch-2 chunk partials (coalesced, 4 thr/row) ----------
__global__ void __launch_bounds__(256) combine_kernel(
    const u32* __restrict__ po32, const float* __restrict__ ps,
    float* __restrict__ out) {
  int gid = blockIdx.x*256 + threadIdx.x;   // 0..131071
  int row = gid >> 2, part = gid & 3;       // row 0..32767; part = 8-float group
  float sden = ps[row] + ps[32768 + row] + ps[65536 + row] + ps[98304 + row];
  float inv = 1.f/sden;
  float o[8];
  #pragma unroll
  for (int i = 0; i < 8; ++i) o[i] = 0.f;
  #pragma unroll
  for (int chunk = 0; chunk < 4; ++chunk) {
    const u32* pp = po32 + ((size_t)chunk*32768 + row)*16 + part*4;
    uint4 a = *(const uint4*)pp;            // coalesced 16B
    u32 av[4] = {a.x, a.y, a.z, a.w};
    #pragma unroll
    for (int j = 0; j < 4; ++j) {
      o[2*j]   += __uint_as_float(av[j] << 16);
      o[2*j+1] += __uint_as_float(av[j] & 0xffff0000u);
    }
  }
  int bh = row >> 12, n = row & 4095;
  float* op = out + ((size_t)(((bh>>2)*NC + (bh&3)*64 + (n>>6))*64 + (n&63)))*64 + 32 + part*8;
  #pragma unroll
  for (int j = 0; j < 2; ++j) {
    f32x4 v = {o[4*j]*inv, o[4*j+1]*inv, o[4*j+2]*inv, o[4*j+3]*inv};
    *(f32x4*)(op + 4*j) = v;
  }
}

extern "C" void kernel_launch(void* const* d_in, const int* in_sizes, int n_in,
                              void* d_out, int out_size, void* d_ws, size_t ws_size,
                              hipStream_t stream) {
  const float* x    = (const float*)d_in[0];
  const float* rpe  = (const float*)d_in[1];
  const float* qw   = (const float*)d_in[2];
  const float* qb   = (const float*)d_in[3];
  const float* kvw  = (const float*)d_in[4];
  const float* kvb  = (const float*)d_in[5];
  const float* dw1  = (const float*)d_in[6];
  const float* bn11 = (const float*)d_in[7];
  const float* pw1  = (const float*)d_in[8];
  const float* bn12 = (const float*)d_in[9];
  const float* dw2  = (const float*)d_in[10];
  const float* bn21 = (const float*)d_in[11];
  const float* pw2  = (const float*)d_in[12];
  const float* bn22 = (const float*)d_in[13];
  const float* lw   = (const float*)d_in[14];
  const float* lb   = (const float*)d_in[15];
  float* out = (float*)d_out;
  float* ws  = (float*)d_ws;

  float* t1   = ws + OFF_T1;
  float* t2   = ws + OFF_T2;
  u16*   q    = (u16*)(ws + OFF_Q);
  u16*   kt1  = (u16*)(ws + OFF_KT1);
  u16*   vt1  = (u16*)(ws + OFF_VT1);
  u16*   kt2  = (u16*)(ws + OFF_KT2);
  u16*   vt2  = (u16*)(ws + OFF_VT2);
  u16*   rct1 = (u16*)(ws + OFF_RCT1);
  u16*   rct2 = (u16*)(ws + OFF_RCT2);
  u32*   po32 = (u32*)(ws + OFF_PO);
  float* ps   = ws + OFF_PS;

  hipLaunchKernelGGL(prep_kernel, dim3(3840), dim3(256), 0, stream,
                     x, dw1, bn11, pw1, bn12, t1, dw2, bn21, pw2, bn22, t2,
                     rpe, rct1, rct2);
  hipLaunchKernelGGL(localkv_kernel, dim3(1664), dim3(256), 0, stream,
                     t1, t2, lw, lb, kvw, kvb, kt1, vt1, kt2, vt2, x, qw, qb, q);
  hipLaunchKernelGGL(attn_kernel, dim3(2560), dim3(256), 0, stream,
                     q, kt1, vt1, rct1, kt2, vt2, rct2, po32, ps, out);
  hipLaunchKernelGGL(combine_kernel, dim3(512), dim3(256), 0, stream,
                     po32, ps, out);
}

// Round 5
// 177.888 us; speedup vs baseline: 1.1693x; 1.1693x over previous
//
#include <hip/hip_runtime.h>
#include <hip/hip_bf16.h>
#include <math.h>

#define NB 2
#define NC 256
#define HWIN 4096
#define NN 4096
#define ND 32
#define NHH 4
#define EPSV 1e-5f

typedef short short8 __attribute__((ext_vector_type(8)));
typedef float f32x4 __attribute__((ext_vector_type(4)));
typedef unsigned short u16;
typedef unsigned int u32;

// workspace offsets (float32 units)
#define OFF_T1   0          // 131072
#define OFF_T2   262144     // 524288
#define OFF_Q    1310720    // 524288 (bf16 x 1048576)
#define OFF_KT1  1835008    // 65536
#define OFF_VT1  1900544    // 65536
#define OFF_KT2  1966080    // 262144
#define OFF_VT2  2228224    // 262144
#define OFF_RCT1 2490368    // 40960
#define OFF_RCT2 2531328    // 163840
#define OFF_WT   2695168    // 131072  (kvw packed: wtp[c4][o][4], f32)
#define OFF_PO   2826240    // 2097152 u32: po[chunk][32768 rows][16]
#define OFF_PS   4923392    // 131072: ps[chunk][32768 rows]
#define OFF_QWT  5054464    // 32768   (qw packed: qwtp[c4][oc][4], f32)
// end 5087232 floats = 20.3 MB

#define QSCALE 0.2550437314857726f   // 1/sqrt(32) * log2(e)
#define LOG2E  1.4426950408889634f

__device__ __forceinline__ u16 f2bf(float x) {   // f32 -> bf16 RNE
  unsigned u = __float_as_uint(x);
  u += 0x7fffu + ((u >> 16) & 1u);
  return (u16)(u >> 16);
}

__device__ __forceinline__ u32 pk_bf16(float a, float b) {  // packed RNE cvt
  __hip_bfloat162 h = __float22bfloat162_rn(make_float2(a, b));
  u32 r; __builtin_memcpy(&r, &h, 4);
  return r;
}

__device__ __forceinline__ float keysw(float t) {  // Keys cubic, a=-0.5
  t = fabsf(t);
  float w;
  if (t < 1.f)       w = ((1.5f*t - 2.5f)*t)*t + 1.f;
  else if (t < 2.f)  w = ((-0.5f*t + 2.5f)*t - 4.f)*t + 2.f;
  else               w = 0.f;
  return w;
}

// ---------- device bodies ----------
template<int KS, int STR, int PAD, int OH>
__device__ __forceinline__ void dwconv_body(int idx, const float* __restrict__ x,
    const float* __restrict__ dww, const float* __restrict__ bn1,
    const float* __restrict__ pww, const float* __restrict__ bn2,
    float* __restrict__ tout) {
  const int hw = OH*OH;
  int s = idx % hw; int c = (idx/hw) % NC; int b = idx/(hw*NC);
  int oy = s / OH, ox = s % OH;
  const float* xp = x + (b*NC + c)*HWIN;
  const float* wp = dww + c*KS*KS;
  float acc = 0.f;
  #pragma unroll
  for (int ky = 0; ky < KS; ++ky) {
    int iy = oy*STR - PAD + ky;
    if (iy < 0 || iy >= 64) continue;
    #pragma unroll
    for (int kx = 0; kx < KS; ++kx) {
      int ix = ox*STR - PAD + kx;
      if (ix < 0 || ix >= 64) continue;
      acc += xp[iy*64 + ix] * wp[ky*KS + kx];
    }
  }
  float s1 = bn1[c] * rsqrtf(bn1[3*NC + c] + EPSV);
  float z = (acc - bn1[2*NC + c])*s1 + bn1[NC + c];
  z = fmaxf(z, 0.f);
  float s2 = bn2[c] * rsqrtf(bn2[3*NC + c] + EPSV);
  z = z * (pww[c]*s2) + (bn2[NC + c] - bn2[2*NC + c]*s2);
  tout[idx] = z;
}

__device__ __forceinline__ void rpe_body(int idx, const float* __restrict__ rpe,
                                         u16* __restrict__ rcT, int L, int ch) {
  int r = idx & 63; int l = (idx >> 6) % L; int b = idx / (64*L);
  float f = ((float)l + 0.5f)*(64.f/(float)L) - 0.5f;
  int i0 = (int)floorf(f) - 1;
  const float* rp = rpe + ((b*2 + ch)*64 + r)*64;
  float v = 0.f, wsum = 0.f;
  #pragma unroll
  for (int j = 0; j < 4; ++j) {
    int i = i0 + j;
    if (i >= 0 && i < 64) {
      float w = keysw(f - (float)i);
      v += w * rp[i]; wsum += w;
    }
  }
  rcT[((size_t)(b*L + l))*80 + 4 + r] = f2bf(v / wsum);
}

// ---------- stage 1: dwconv1 + dwconv2 + rpe1 + rpe2 + weight repack ----------
// Weight repack: wtp[(c4*512 + o)*4 + j] = kvw[o*256 + c4*4 + j]
//                qwtp[(c4*128 + oc)*4 + j] = qw[oc*256 + c4*4 + j]
// -> stage-2 weight loads are float4 (4 channels) AND lane-coalesced over o.
__global__ void __launch_bounds__(256) prep_kernel(
    const float* __restrict__ x,
    const float* __restrict__ dw1, const float* __restrict__ bn11,
    const float* __restrict__ pw1, const float* __restrict__ bn12, float* __restrict__ t1,
    const float* __restrict__ dw2, const float* __restrict__ bn21,
    const float* __restrict__ pw2, const float* __restrict__ bn22, float* __restrict__ t2,
    const float* __restrict__ rpe, u16* __restrict__ rct1, u16* __restrict__ rct2,
    const float* __restrict__ kvw, float* __restrict__ wtp,
    const float* __restrict__ qw, float* __restrict__ qwtp) {
  int blk = blockIdx.x;
  int t = threadIdx.x;
  if (blk < 512) {
    dwconv_body<7,4,3,16>(blk*256 + t, x, dw1, bn11, pw1, bn12, t1);
  } else if (blk < 2560) {
    dwconv_body<5,2,2,32>((blk-512)*256 + t, x, dw2, bn21, pw2, bn22, t2);
  } else if (blk < 2816) {
    rpe_body((blk-2560)*256 + t, rpe, rct1, 512, 0);
  } else if (blk < 3840) {
    rpe_body((blk-2816)*256 + t, rpe, rct2, 2048, 1);
  } else if (blk < 3968) {
    // kvw repack: idx -> o = idx>>6, c4 = idx&63 (read coalesced)
    int idx = (blk-3840)*256 + t;          // 0..32767
    float4 vv = *(const float4*)(kvw + (size_t)idx*4);
    int o = idx >> 6, c4 = idx & 63;
    *(float4*)(wtp + ((size_t)(c4*512 + o))*4) = vv;
  } else {
    // qw repack
    int idx = (blk-3968)*256 + t;          // 0..8191
    float4 vv = *(const float4*)(qw + (size_t)idx*4);
    int oc = idx >> 6, c4 = idx & 63;
    *(float4*)(qwtp + ((size_t)(c4*128 + oc))*4) = vv;
  }
}

// ---------- stage 2: fused local 3x3 + kv 1x1 (both branches) + q 1x1 ----------
// blocks [0,640): strip blocks, PAIRED: even=K half, odd=V half (stage A local
//   conv recomputed by both). blocks [640,1664): q conv, 8 spatial/block.
// Stage B: packed-channel weights (wtp/qwtp): per c4 one float4 load that is
//   lane-coalesced (wave = 1KB contiguous) AND carries 4 channels -> 32 FMA
//   per load (vs R3's 16cy/load scalar-column chain; vs R4's uncoalesced rows).
//   Arithmetic order identical to R3 (ascending c).
__global__ void __launch_bounds__(256) localkv_kernel(
    const float* __restrict__ t1in, const float* __restrict__ t2in,
    const float* __restrict__ lw, const float* __restrict__ lb,
    const float* __restrict__ wtp, const float* __restrict__ kvb,
    u16* __restrict__ kt1, u16* __restrict__ vt1,
    u16* __restrict__ kt2, u16* __restrict__ vt2,
    const float* __restrict__ x, const float* __restrict__ qwtp,
    const float* __restrict__ qb, u16* __restrict__ q) {
  __shared__ float sbuf[NC*8];   // 8KB
  int blk = blockIdx.x, tid = threadIdx.x;
  if (blk < 640) {
    // ---- fused local+kv over an 8-spatial strip; this block does K or V ----
    int si = blk >> 1, kv = blk & 1;
    const float* tin; u16 *kT, *vT; int OH, hw, b, s0;
    if (si < 64) { tin = t1in; kT = kt1; vT = vt1; OH = 16; hw = 256;  b = si >> 5;  s0 = (si & 31)*8; }
    else { int v = si-64; tin = t2in; kT = kt2; vT = vt2; OH = 32; hw = 1024; b = v >> 7; s0 = (v & 127)*8; }
    int oy = s0 / OH, ox0 = s0 % OH;
    // stage A: y(strip) -> LDS, stride 8 (2-way LDS aliasing = free)
    int ci = tid >> 3, i = tid & 7;
    int ox = ox0 + i;
    #pragma unroll
    for (int p = 0; p < 8; ++p) {
      int c = p*32 + ci;
      const float* tp = tin + (b*NC + c)*hw;
      const float* wp = lw + c*9;
      float acc = lb[c];
      #pragma unroll
      for (int dy = 0; dy < 3; ++dy) {
        int iy = oy + dy - 1;
        if (iy < 0 || iy >= OH) continue;
        #pragma unroll
        for (int dx = 0; dx < 3; ++dx) {
          int ix = ox + dx - 1;
          if (ix < 0 || ix >= OH) continue;
          acc += tp[iy*OH + ix]*wp[dy*3 + dx];
        }
      }
      acc += tp[oy*OH + ox];
      sbuf[c*8 + i] = acc;
    }
    __syncthreads();
    // stage B: this thread computes output row o = tid + kv*256, 8 spatial.
    float acc[8];
    float bias = kvb[tid + kv*256];
    #pragma unroll
    for (int j = 0; j < 8; ++j) acc[j] = bias;
    const float* wrow = wtp + (size_t)(tid + kv*256)*4;   // + c4*2048
    #pragma unroll 4
    for (int c4 = 0; c4 < 64; ++c4) {
      f32x4 w4 = *(const f32x4*)(wrow + (size_t)c4*2048);
      #pragma unroll
      for (int j = 0; j < 4; ++j) {
        int c = c4*4 + j;
        f32x4 ya = *(const f32x4*)(sbuf + c*8);
        f32x4 yb = *(const f32x4*)(sbuf + c*8 + 4);
        float wv = w4[j];
        #pragma unroll
        for (int jj = 0; jj < 4; ++jj) { acc[jj] += wv*ya[jj]; acc[4+jj] += wv*yb[jj]; }
      }
    }
    int hh2 = tid >> 6, r = tid & 63, d = r >> 1, e = r & 1;
    int L = 2*hw;
    if (kv == 0) {
      u16* kp = kT + ((size_t)((b*NHH + hh2)*L + e*hw + s0))*ND + d;
      #pragma unroll
      for (int j = 0; j < 8; ++j) kp[j*ND] = f2bf(acc[j]);
    } else {
      // V tiled write: l = e*hw + s0 + j, tile = l>>6 (const per thread)
      int l0v = e*hw + s0;
      u16* vp = vT + ((size_t)((b*NHH + hh2)*(L/64) + (l0v >> 6))*ND + d)*64 + (l0v & 63);
      #pragma unroll
      for (int j = 0; j < 8; ++j) vp[j] = f2bf(acc[j]);
    }
  } else {
    // ---- q conv: 8 spatial/block, packed-channel qwtp weights ----
    int blk2 = blk - 640;           // 0..1023
    int b = blk2 >> 9;
    int n0 = (blk2 & 511) * 8;
    #pragma unroll
    for (int j = 0; j < 8; ++j) {
      int idx = tid + 256*j;
      int c = idx >> 3, i = idx & 7;
      sbuf[idx] = x[(b*NC + c)*HWIN + n0 + i];
    }
    __syncthreads();
    int sph = tid >> 7, oc = tid & 127;    // sph: spatial half (4 each)
    float bias = qb[oc];
    float acc[4];
    #pragma unroll
    for (int i = 0; i < 4; ++i) acc[i] = bias;
    const float* wrow = qwtp + (size_t)oc*4;   // + c4*512
    #pragma unroll 4
    for (int c4 = 0; c4 < 64; ++c4) {
      f32x4 w4 = *(const f32x4*)(wrow + (size_t)c4*512);
      #pragma unroll
      for (int j = 0; j < 4; ++j) {
        int c = c4*4 + j;
        f32x4 yv = *(const f32x4*)(sbuf + c*8 + sph*4);
        float wv = w4[j];
        #pragma unroll
        for (int i = 0; i < 4; ++i) acc[i] += wv * yv[i];
      }
    }
    int h = oc >> 5, d = oc & 31;
    u16* qp = q + (((size_t)(b*NHH + h))*NN + n0 + sph*4)*ND + d;
    #pragma unroll
    for (int i = 0; i < 4; ++i) qp[i*ND] = f2bf(acc[i]*QSCALE);
  }
}

// ---------- stage 3: MFMA flash attention ----------
// Single-buffered LDS K/V, reg prefetch, 2 barriers/iter; raw v_exp_f32;
// XOR-swizzled LDS (conflict-free); V staged from tiled global layout.
// K tile 64 rows x 64B:  byte = row*64  + (cb ^ (((row>>1)&3)<<4))
// V tile 32 rows x 128B: byte = row*128 + (cb ^ ((row&7)<<4))
// P tile 16 rows x 128B: byte = row*128 + (cb ^ ((row&7)<<4))
__global__ void __launch_bounds__(256) attn_kernel(
    const u16* __restrict__ qbf,
    const u16* __restrict__ kt1, const u16* __restrict__ vt1, const u16* __restrict__ rct1,
    const u16* __restrict__ kt2, const u16* __restrict__ vt2, const u16* __restrict__ rct2,
    u32* __restrict__ po32, float* __restrict__ ps,
    float* __restrict__ out) {
  __shared__ u16 kbuf[64*32];          // K tile, swizzled, 4KB
  __shared__ u16 vbuf[32*64];          // V tile, swizzled, 4KB
  __shared__ u32 pbuf_all[4][16*32];   // per-wave P^T tile, swizzled, 2KB/wave
  int u = blockIdx.x;
  int br, b, hh, rb, chunk;
  if (u < 512) { br = 0; b = u >> 8; hh = (u >> 6) & 3; rb = u & 63; chunk = 0; }
  else { int v = u - 512; br = 1; chunk = v & 3; rb = (v >> 2) & 63; hh = (v >> 8) & 3; b = v >> 10; }
  int L = br ? 2048 : 512;
  const u16* kT  = br ? kt2 : kt1;
  const u16* vT  = br ? vt2 : vt1;
  const u16* rcT = br ? rct2 : rct1;
  int l0base = chunk * 512;
  int tid = threadIdx.x;
  int w = tid >> 6, lane = tid & 63;
  int g = lane >> 4, lo = lane & 15;
  u32* pbuf = pbuf_all[w];
  u16* pbuf16 = (u16*)pbuf;
  int n = rb*64 + w*16 + lo;

  const u16* kbase = kT + (size_t)(b*NHH + hh)*L*ND;
  const u16* vbase = vT + (size_t)(b*NHH + hh)*ND*L;   // tiled: [L/64][32][64]
  const u16* rcTb  = rcT + (size_t)b*L*80;

  // Q B-frag (pre-scaled by 1/sqrt(32)*log2e)
  short8 qf = *(const short8*)(qbf + (((size_t)(b*NHH + hh))*NN + n)*ND + 8*g);

  // tap-weight B-frag for RPE ext-MFMA
  float fr = ((float)n + 0.5f)*(1.f/64.f) - 0.5f;
  int ri0 = (int)floorf(fr) - 1;
  int a = (w < 2) ? rb - 2 : rb - 1;     // wave-uniform floor(fr(q0)) - 1
  int rmin = a & ~3;
  float wr4[4]; float wsum = 0.f;
  #pragma unroll
  for (int j = 0; j < 4; ++j) {
    int i = ri0 + j;
    float wv = (i >= 0 && i < 64) ? keysw(fr - (float)i) : 0.f;
    wr4[j] = wv; wsum += wv;
  }
  float invw = LOG2E / wsum;
  float wt8[8];
  #pragma unroll
  for (int s = 0; s < 8; ++s) {
    float acc = 0.f;
    #pragma unroll
    for (int j = 0; j < 4; ++j)
      acc += (ri0 + j - rmin == s) ? wr4[j]*invw : 0.f;
    wt8[s] = acc;
  }
  short8 wtf;
  {
    u32 p0 = pk_bf16(wt8[0], wt8[1]), p1 = pk_bf16(wt8[2], wt8[3]);
    u32 p2 = pk_bf16(wt8[4], wt8[5]), p3 = pk_bf16(wt8[6], wt8[7]);
    uint4 uu = make_uint4(p0, p1, p2, p3);
    wtf = __builtin_bit_cast(short8, uu);
    if (g != 0) wtf = (short8)0;
  }
  const u16* rcrow0 = rcTb + (rmin + 4);

  const f32x4 zero = {0.f, 0.f, 0.f, 0.f};
  float ssum = 0.f;
  f32x4 o0 = zero, o1 = zero;

  // staging lane roles + swizzle constants
  int kr_row = tid >> 2, kr_col = (tid & 3)*8;   // K: 64 rows x 32 u16
  int kr_sw  = ((kr_row >> 1) & 3)*8;
  int vr_row = tid >> 3, vr_col = (tid & 7)*8;   // V: 32 rows x 64 u16
  int vr_sw  = (vr_row & 7)*8;
  // compute-side swizzles (row-dependent parts only)
  int ksw = ((lo >> 1) & 3)*8;                   // K row 16c+lo -> same as lo
  int vsw = (lo & 7)*8;                          // V rows lo, 16+lo share
  int psw4 = (lo & 7)*4;                         // pbuf u32 swizzle
  int psw8 = (lo & 7)*8;                         // pbuf u16 swizzle

  auto stageLoad = [&](short8& kr, short8& vr, int l0) {
    kr = *(const short8*)(kbase + (size_t)(l0 + kr_row)*ND + kr_col);
    vr = *(const short8*)(vbase + (size_t)(l0 >> 6)*(ND*64) + vr_row*64 + vr_col);
  };
  auto stageStore = [&](short8 kr, short8 vr) {
    *(short8*)(kbuf + kr_row*32 + (kr_col ^ kr_sw)) = kr;
    *(short8*)(vbuf + vr_row*64 + (vr_col ^ vr_sw)) = vr;
  };
  auto loadRC = [&](uint4 (&rc)[4], int l0) {
    #pragma unroll
    for (int c = 0; c < 4; ++c) {
      const u16* arow = rcrow0 + (size_t)(l0 + 16*c + lo)*80;
      uint2 ra = *(const uint2*)arow;
      uint2 rb2 = *(const uint2*)(arow + 4);
      rc[c] = make_uint4(ra.x, ra.y, rb2.x, rb2.y);
    }
  };

  short8 kr, vr;
  uint4 rcA[4], rcB[4];
  stageLoad(kr, vr, l0base);
  loadRC(rcA, l0base);

  for (int t = 0; t < 8; ++t) {
    stageStore(kr, vr);
    __syncthreads();
    if (t < 7) { stageLoad(kr, vr, l0base + (t+1)*64); loadRC(rcB, l0base + (t+1)*64); }
    // S tiles: rc ext-MFMA chained into K.Q MFMA
    f32x4 s4[4];
    #pragma unroll
    for (int c = 0; c < 4; ++c) {
      short8 rcf = __builtin_bit_cast(short8, rcA[c]);
      f32x4 accr = __builtin_amdgcn_mfma_f32_16x16x32_bf16(rcf, wtf, zero, 0, 0, 0);
      short8 kf = *(const short8*)(kbuf + (16*c + lo)*32 + ((8*g) ^ ksw));
      s4[c] = __builtin_amdgcn_mfma_f32_16x16x32_bf16(kf, qf, accr, 0, 0, 0);
    }
    // max-free softmax: p = exp2(s), raw v_exp_f32 (inputs bounded, P->bf16)
    float psum = 0.f;
    u32 pk[8];
    #pragma unroll
    for (int c = 0; c < 4; ++c) {
      float p0 = __builtin_amdgcn_exp2f(s4[c][0]);
      float p1 = __builtin_amdgcn_exp2f(s4[c][1]);
      float p2 = __builtin_amdgcn_exp2f(s4[c][2]);
      float p3 = __builtin_amdgcn_exp2f(s4[c][3]);
      psum += (p0 + p1) + (p2 + p3);
      pk[2*c]   = pk_bf16(p0, p1);
      pk[2*c+1] = pk_bf16(p2, p3);
    }
    ssum += psum;
    #pragma unroll
    for (int c = 0; c < 4; ++c)
      *(uint2*)(pbuf + lo*32 + ((8*c + 2*g) ^ psw4)) = make_uint2(pk[2*c], pk[2*c+1]);
    short8 pf0 = *(const short8*)(pbuf16 + lo*64 + ((8*g) ^ psw8));
    short8 pf1 = *(const short8*)(pbuf16 + lo*64 + ((32 + 8*g) ^ psw8));
    short8 v00 = *(const short8*)(vbuf + lo*64 + ((8*g) ^ vsw));
    short8 v01 = *(const short8*)(vbuf + lo*64 + ((32 + 8*g) ^ vsw));
    short8 v10 = *(const short8*)(vbuf + (16 + lo)*64 + ((8*g) ^ vsw));
    short8 v11 = *(const short8*)(vbuf + (16 + lo)*64 + ((32 + 8*g) ^ vsw));
    o0 = __builtin_amdgcn_mfma_f32_16x16x32_bf16(v00, pf0, o0, 0, 0, 0);
    o1 = __builtin_amdgcn_mfma_f32_16x16x32_bf16(v10, pf0, o1, 0, 0, 0);
    o0 = __builtin_amdgcn_mfma_f32_16x16x32_bf16(v01, pf1, o0, 0, 0, 0);
    o1 = __builtin_amdgcn_mfma_f32_16x16x32_bf16(v11, pf1, o1, 0, 0, 0);
    if (t < 7) {
      #pragma unroll
      for (int j = 0; j < 4; ++j) rcA[j] = rcB[j];
    }
    __syncthreads();   // all reads done before next tile's store
  }

  ssum += __shfl_xor(ssum, 16, 64);
  ssum += __shfl_xor(ssum, 32, 64);
  if (br == 0) {
    float inv = 1.f/ssum;
    f32x4 w0 = o0*inv, w1 = o1*inv;
    float* op = out + ((size_t)((b*NC + hh*64 + rb)*64 + (w*16 + lo)))*64;
    *(f32x4*)(op + 4*g)      = w0;
    *(f32x4*)(op + 16 + 4*g) = w1;
  } else {
    int bh = b*NHH + hh;
    int row = bh*NN + n;
    u32* pop = po32 + ((size_t)chunk*32768 + row)*16;    // chunk-major
    pop[2*g]     = pk_bf16(o0[0], o0[1]);
    pop[2*g + 1] = pk_bf16(o0[2], o0[3]);
    pop[8 + 2*g]     = pk_bf16(o1[0], o1[1]);
    pop[8 + 2*g + 1] = pk_bf16(o1[2], o1[3]);
    if (g == 0) ps[(size_t)chunk*32768 + row] = ssum;
  }
}

// ---------- stage 4: combine branch-2 chunk partials (coalesced, 4 thr/row) ----------
__global__ void __launch_bounds__(256) combine_kernel(
    const u32* __restrict__ po32, const float* __restrict__ ps,
    float* __restrict__ out) {
  int gid = blockIdx.x*256 + threadIdx.x;   // 0..131071
  int row = gid >> 2, part = gid & 3;       // row 0..32767; part = 8-float group
  float sden = ps[row] + ps[32768 + row] + ps[65536 + row] + ps[98304 + row];
  float inv = 1.f/sden;
  float o[8];
  #pragma unroll
  for (int i = 0; i < 8; ++i) o[i] = 0.f;
  #pragma unroll
  for (int chunk = 0; chunk < 4; ++chunk) {
    const u32* pp = po32 + ((size_t)chunk*32768 + row)*16 + part*4;
    uint4 a = *(const uint4*)pp;            // coalesced 16B
    u32 av[4] = {a.x, a.y, a.z, a.w};
    #pragma unroll
    for (int j = 0; j < 4; ++j) {
      o[2*j]   += __uint_as_float(av[j] << 16);
      o[2*j+1] += __uint_as_float(av[j] & 0xffff0000u);
    }
  }
  int bh = row >> 12, n = row & 4095;
  float* op = out + ((size_t)(((bh>>2)*NC + (bh&3)*64 + (n>>6))*64 + (n&63)))*64 + 32 + part*8;
  #pragma unroll
  for (int j = 0; j < 2; ++j) {
    f32x4 v = {o[4*j]*inv, o[4*j+1]*inv, o[4*j+2]*inv, o[4*j+3]*inv};
    *(f32x4*)(op + 4*j) = v;
  }
}

extern "C" void kernel_launch(void* const* d_in, const int* in_sizes, int n_in,
                              void* d_out, int out_size, void* d_ws, size_t ws_size,
                              hipStream_t stream) {
  const float* x    = (const float*)d_in[0];
  const float* rpe  = (const float*)d_in[1];
  const float* qw   = (const float*)d_in[2];
  const float* qb   = (const float*)d_in[3];
  const float* kvw  = (const float*)d_in[4];
  const float* kvb  = (const float*)d_in[5];
  const float* dw1  = (const float*)d_in[6];
  const float* bn11 = (const float*)d_in[7];
  const float* pw1  = (const float*)d_in[8];
  const float* bn12 = (const float*)d_in[9];
  const float* dw2  = (const float*)d_in[10];
  const float* bn21 = (const float*)d_in[11];
  const float* pw2  = (const float*)d_in[12];
  const float* bn22 = (const float*)d_in[13];
  const float* lw   = (const float*)d_in[14];
  const float* lb   = (const float*)d_in[15];
  float* out = (float*)d_out;
  float* ws  = (float*)d_ws;

  float* t1   = ws + OFF_T1;
  float* t2   = ws + OFF_T2;
  u16*   q    = (u16*)(ws + OFF_Q);
  u16*   kt1  = (u16*)(ws + OFF_KT1);
  u16*   vt1  = (u16*)(ws + OFF_VT1);
  u16*   kt2  = (u16*)(ws + OFF_KT2);
  u16*   vt2  = (u16*)(ws + OFF_VT2);
  u16*   rct1 = (u16*)(ws + OFF_RCT1);
  u16*   rct2 = (u16*)(ws + OFF_RCT2);
  float* wtp  = ws + OFF_WT;
  u32*   po32 = (u32*)(ws + OFF_PO);
  float* ps   = ws + OFF_PS;
  float* qwtp = ws + OFF_QWT;

  hipLaunchKernelGGL(prep_kernel, dim3(4000), dim3(256), 0, stream,
                     x, dw1, bn11, pw1, bn12, t1, dw2, bn21, pw2, bn22, t2,
                     rpe, rct1, rct2, kvw, wtp, qw, qwtp);
  hipLaunchKernelGGL(localkv_kernel, dim3(1664), dim3(256), 0, stream,
                     t1, t2, lw, lb, wtp, kvb, kt1, vt1, kt2, vt2, x, qwtp, qb, q);
  hipLaunchKernelGGL(attn_kernel, dim3(2560), dim3(256), 0, stream,
                     q, kt1, vt1, rct1, kt2, vt2, rct2, po32, ps, out);
  hipLaunchKernelGGL(combine_kernel, dim3(512), dim3(256), 0, stream,
                     po32, ps, out);
}